// Round 1
// 150.825 us; speedup vs baseline: 1.0258x; 1.0258x over previous
//
#include <hip/hip_runtime.h>
#include <math.h>

constexpr int L = 32768;
constexpr int H = 256;
constexpr int P = 256;
constexpr int T = 64;        // scan chunk length
constexpr int NC = L / T;    // 512 chunks
constexpr int N1 = 2 * P;    // 512: X concat width, INTERLEAVED col = 2p+{0:re,1:im}
constexpr int LDA = 40;      // padded LDS A row stride (shorts): conflict-free frag reads
constexpr int LDEP = 130;    // epilogue LDS row stride (floats)

typedef __attribute__((ext_vector_type(8))) short short8;
typedef __attribute__((ext_vector_type(4))) float f32x4;

// ---------------- bf16 helpers (RNE) ----------------
__device__ __forceinline__ unsigned f2bf(float f) {
  unsigned u = __float_as_uint(f);
  return (u + 0x7FFFu + ((u >> 16) & 1u)) >> 16;
}
__device__ __forceinline__ float bf_lo(unsigned u) { return __uint_as_float(u << 16); }
__device__ __forceinline__ float bf_hi(unsigned u) { return __uint_as_float(u & 0xFFFF0000u); }

__device__ __forceinline__ void gload_lds16(const unsigned short* g, unsigned short* l) {
  __builtin_amdgcn_global_load_lds(
      (const __attribute__((address_space(1))) unsigned int*)(g),
      (__attribute__((address_space(3))) unsigned int*)(l), 16, 0, 0);
}

// Counted-vmcnt barrier: B-tile gloads must have landed (oldest), deeper
// register prefetches stay in flight. lgkmcnt(0) publishes this wave's
// ds_writes and completes its ds_reads before the barrier (DS is in-order).
#define KBAR(N) do { \
    asm volatile("s_waitcnt vmcnt(" #N ") lgkmcnt(0)" ::: "memory"); \
    __builtin_amdgcn_s_barrier(); \
    __builtin_amdgcn_sched_barrier(0); \
  } while (0)

// Pin VMEM issue order (ALU/VALU/SALU/MFMA/DS may cross, VMEM may not).
#define VMEM_FENCE() __builtin_amdgcn_sched_barrier(0x38F)

__device__ __forceinline__ void lambda_bar_of(const float* __restrict__ lam,
                                              const float* __restrict__ lstep,
                                              int p, float& lbr, float& lbi) {
  float lr = lam[2 * p], li = lam[2 * p + 1];
  float st = expf(lstep[p]);
  float ea = expf(lr * st);
  lbr = ea * cosf(li * st);
  lbi = ea * sinf(li * st);
}

// ---------------------------------------------------------------------------
// k_prep: Bcat (512 x 256 bf16, rows interleaved: row 2p=Re(B_bar[p]), 2p+1=Im)
//         Ccat (256 x 512 bf16, cols interleaved: col 2p=Re(C[h,p]), 2p+1=-Im)
//         pow  (T x P fp32 planar): lambda_bar^(t+1)
// ---------------------------------------------------------------------------
__global__ __launch_bounds__(256) void k_prep(const float* __restrict__ lam,
                                              const float* __restrict__ lstep,
                                              const float* __restrict__ Bri,
                                              const float* __restrict__ Cri,
                                              unsigned short* __restrict__ Bcat,
                                              unsigned short* __restrict__ Ccat,
                                              float* __restrict__ powr,
                                              float* __restrict__ powi) {
  int idx = blockIdx.x * 256 + threadIdx.x;  // < 278528
  if (idx < N1 * H) {
    int n = idx >> 8, k = idx & 255;
    int p = n >> 1, comp = n & 1;
    float lr = lam[2 * p], li = lam[2 * p + 1];
    float st = expf(lstep[p]);
    float ea = expf(lr * st);
    float lbr = ea * cosf(li * st), lbi = ea * sinf(li * st);
    float inv = 1.0f / (lr * lr + li * li);
    float nr = lbr - 1.0f;
    float fr = (nr * lr + lbi * li) * inv;
    float fi = (lbi * lr - nr * li) * inv;
    float br = Bri[2 * (p * H + k)], bi = Bri[2 * (p * H + k) + 1];
    float v = (comp == 0) ? (fr * br - fi * bi) : (fr * bi + fi * br);
    Bcat[idx] = (unsigned short)f2bf(v);
  } else if (idx < 2 * N1 * H) {
    int j = idx - N1 * H;
    int h = j >> 9, k2 = j & 511;
    int p = k2 >> 1;
    float v = ((k2 & 1) == 0) ? Cri[2 * (h * P + p)] : -Cri[2 * (h * P + p) + 1];
    Ccat[j] = (unsigned short)f2bf(v);
  } else {
    int r = idx - 2 * N1 * H;  // < T*P
    int t = r >> 8, p = r & 255;
    float lr = lam[2 * p], li = lam[2 * p + 1];
    float st = expf(lstep[p]);
    float e = (float)(t + 1);
    float er = expf(e * lr * st);
    powr[r] = er * cosf(e * li * st);
    powi[r] = er * sinf(e * li * st);
  }
}

// ---------------------------------------------------------------------------
// GEMM1 fused: 128x128 tile (2 chunks), dbuf LDS, counted-vmcnt barriers.
// A = sig fp32 -> bf16 manual staging (depth-2 register pipeline).
// B via global_load_lds, FRAGMENT-MAJOR layout (conflict-free ds_read_b128):
//   LDS chunk (j*64+lane) holds B[row=j*16+(lane&15)][k=(lane>>4)*8 ..+7].
// Epilogue: per-chunk LDS dump + in-block scan -> Xl (bf16 interleaved) + S.
// grid (L/128, N1/128) = (256, 4).
// ---------------------------------------------------------------------------
__global__ __launch_bounds__(256, 4) void k_gemm1s(const float* __restrict__ sig,
                                                   const unsigned short* __restrict__ Bcat,
                                                   const float* __restrict__ lam,
                                                   const float* __restrict__ lstep,
                                                   unsigned short* __restrict__ Xl,
                                                   float* __restrict__ Sr,
                                                   float* __restrict__ Si) {
  constexpr int K = 256, NIT = K / 32;
  __shared__ __align__(16) char smem[36864];
  unsigned short* sA[2] = {(unsigned short*)smem, (unsigned short*)smem + 5120};
  unsigned short* sB[2] = {(unsigned short*)smem + 10240, (unsigned short*)smem + 14336};
  float* sEpi = (float*)smem;
  const int tid = threadIdx.x;
  const int lane = tid & 63;
  const int wave = tid >> 6;
  const int wr = (wave >> 1) * 64, wc = (wave & 1) * 64;
  const int m0 = blockIdx.x * 128, n0 = blockIdx.y * 128;
  const int ar = tid >> 1, aq = (tid & 1) * 16;       // A staging: row 0..127, 16-elem half
  const int brow = ((tid >> 6) << 4) | (tid & 15);    // B staging: fragment-major source row
  const int bko = ((tid >> 4) & 3) * 8;               // B staging: k-subgroup (8 shorts)
  const int frow = lane & 15, fk = (lane >> 4) * 8;
  const int hb = (wave & 1) * 2048;                   // this wave's B half base (shorts)
  f32x4 acc[4][4];
#pragma unroll
  for (int i = 0; i < 4; i++)
#pragma unroll
    for (int j = 0; j < 4; j++) acc[i][j] = (f32x4){0.f, 0.f, 0.f, 0.f};

  float4 aR0[4], aR1[4];
  const float* abase = sig + (size_t)(m0 + ar) * K + aq;
#define LOAD_A(R, k0) { const float* s_ = abase + (k0); \
    R[0] = *(const float4*)(s_); R[1] = *(const float4*)(s_ + 4); \
    R[2] = *(const float4*)(s_ + 8); R[3] = *(const float4*)(s_ + 12); }
#define WRITE_A(R, dst) { uint4 w0, w1; \
    w0.x = f2bf(R[0].x) | (f2bf(R[0].y) << 16); w0.y = f2bf(R[0].z) | (f2bf(R[0].w) << 16); \
    w0.z = f2bf(R[1].x) | (f2bf(R[1].y) << 16); w0.w = f2bf(R[1].z) | (f2bf(R[1].w) << 16); \
    w1.x = f2bf(R[2].x) | (f2bf(R[2].y) << 16); w1.y = f2bf(R[2].z) | (f2bf(R[2].w) << 16); \
    w1.z = f2bf(R[3].x) | (f2bf(R[3].y) << 16); w1.w = f2bf(R[3].z) | (f2bf(R[3].w) << 16); \
    *(uint4*)((dst) + ar * LDA + aq) = w0; *(uint4*)((dst) + ar * LDA + aq + 8) = w1; }
#define ISSUE_B(k0, buf) { \
    gload_lds16(Bcat + (size_t)(n0 + brow) * K + (k0) + bko, sB[buf] + tid * 8); \
    gload_lds16(Bcat + (size_t)(n0 + 64 + brow) * K + (k0) + bko, sB[buf] + 2048 + tid * 8); }

  // prologue: issue order [A(k0), A(k32), B(k0), A(k64)] -> wait B => vmcnt(4)
  LOAD_A(aR0, 0);
  LOAD_A(aR1, 32);
  VMEM_FENCE();
  ISSUE_B(0, 0);
  VMEM_FENCE();
  WRITE_A(aR0, sA[0]);
  LOAD_A(aR0, 64);
  KBAR(4);
#pragma unroll
  for (int it = 0; it < NIT; it++) {
    const int cur = it & 1, nxt = cur ^ 1;
    if (it + 1 < NIT) {
      if (((it + 1) & 1) == 0) { WRITE_A(aR0, sA[nxt]); } else { WRITE_A(aR1, sA[nxt]); }
      ISSUE_B((it + 1) * 32, nxt);
    }
    VMEM_FENCE();
    if (it + 3 < NIT) {
      if (((it + 3) & 1) == 0) { LOAD_A(aR0, (it + 3) * 32); } else { LOAD_A(aR1, (it + 3) * 32); }
    }
    short8 af[4], bfr[4];
#pragma unroll
    for (int i = 0; i < 4; i++) af[i] = *(const short8*)(sA[cur] + (wr + i * 16 + frow) * LDA + fk);
#pragma unroll
    for (int j = 0; j < 4; j++) bfr[j] = *(const short8*)(sB[cur] + hb + (j * 64 + lane) * 8);
#pragma unroll
    for (int i = 0; i < 4; i++)
#pragma unroll
      for (int j = 0; j < 4; j++)
        acc[i][j] = __builtin_amdgcn_mfma_f32_16x16x32_bf16(af[i], bfr[j], acc[i][j], 0, 0, 0);
    if (it + 1 < NIT) {
      if (it + 3 < NIT) { KBAR(4); } else { KBAR(0); }
    }
  }
  __syncthreads();

  // ---- epilogue: per chunk-half: dump rows to LDS, scan, store ----
  const int crow = (lane >> 4) * 4, ccol = wc + (lane & 15);
#pragma unroll
  for (int half = 0; half < 2; half++) {
    if ((wave >> 1) == half) {
#pragma unroll
      for (int i = 0; i < 4; i++)
#pragma unroll
        for (int j = 0; j < 4; j++)
#pragma unroll
          for (int g = 0; g < 4; g++)
            sEpi[(crow + i * 16 + g) * LDEP + ccol + j * 16] = acc[i][j][g];
    }
    __syncthreads();
    if (tid < 64) {
      const int pl = tid;
      const int gp = (n0 >> 1) + pl;
      const int c = blockIdx.x * 2 + half;
      float lbr, lbi;
      lambda_bar_of(lam, lstep, gp, lbr, lbi);
      float xr = 0.f, xi = 0.f;
      const float* e = sEpi + 2 * pl;
      const size_t gbase = (size_t)(m0 + half * 64) * N1 + n0 + 2 * pl;
      for (int tb = 0; tb < T; tb += 8) {
        float2 v[8];
#pragma unroll
        for (int u = 0; u < 8; u++) v[u] = *(const float2*)(e + (tb + u) * LDEP);
        unsigned ov[8];
#pragma unroll
        for (int u = 0; u < 8; u++) {
          float nr = fmaf(lbr, xr, fmaf(-lbi, xi, v[u].x));
          float ni = fmaf(lbr, xi, fmaf(lbi, xr, v[u].y));
          xr = nr; xi = ni;
          ov[u] = f2bf(xr) | (f2bf(xi) << 16);
        }
#pragma unroll
        for (int u = 0; u < 8; u++)
          *(unsigned*)(Xl + gbase + (size_t)(tb + u) * N1) = ov[u];
      }
      Sr[c * P + gp] = xr;
      Si[c * P + gp] = xi;
    }
    __syncthreads();
  }
#undef LOAD_A
#undef WRITE_A
#undef ISSUE_B
}

// ---------------------------------------------------------------------------
// Parallel carry scan: 256 blocks (one per p) x 64 threads (1 wave).
// ---------------------------------------------------------------------------
__global__ __launch_bounds__(64) void k_carry2(const float* __restrict__ lam,
                                               const float* __restrict__ lstep,
                                               const float* __restrict__ Sr,
                                               const float* __restrict__ Si,
                                               float* __restrict__ car, float* __restrict__ cai) {
  const int p = blockIdx.x;
  const int t = threadIdx.x;  // 0..63
  float lr = lam[2 * p], li = lam[2 * p + 1];
  float st = expf(lstep[p]);
  float eT = expf((float)T * lr * st);
  float lTr = eT * cosf((float)T * li * st);
  float lTi = eT * sinf((float)T * li * st);
  float vr[8], vi[8];
#pragma unroll
  for (int u = 0; u < 8; u++) {
    vr[u] = Sr[(t * 8 + u) * P + p];
    vi[u] = Si[(t * 8 + u) * P + p];
  }
  float Br = 0.f, Bi = 0.f;
#pragma unroll
  for (int u = 0; u < 8; u++) {
    float nr = fmaf(lTr, Br, fmaf(-lTi, Bi, vr[u]));
    float ni = fmaf(lTr, Bi, fmaf(lTi, Br, vi[u]));
    Br = nr; Bi = ni;
  }
  float e8 = expf(8.0f * (float)T * lr * st);
  float Ar = e8 * cosf(8.0f * (float)T * li * st);
  float Ai = e8 * sinf(8.0f * (float)T * li * st);
#pragma unroll
  for (int d = 1; d < 64; d <<= 1) {
    float Aor = __shfl_up(Ar, d), Aoi = __shfl_up(Ai, d);
    float Bor = __shfl_up(Br, d), Boi = __shfl_up(Bi, d);
    if (t >= d) {
      float nBr = Ar * Bor - Ai * Boi + Br;
      float nBi = Ar * Boi + Ai * Bor + Bi;
      float nAr = Aor * Ar - Aoi * Ai;
      float nAi = Aor * Ai + Aoi * Ar;
      Br = nBr; Bi = nBi; Ar = nAr; Ai = nAi;
    }
  }
  float cr = __shfl_up(Br, 1), ci = __shfl_up(Bi, 1);
  if (t == 0) { cr = 0.f; ci = 0.f; }
#pragma unroll
  for (int u = 0; u < 8; u++) {
    car[(t * 8 + u) * P + p] = cr;
    cai[(t * 8 + u) * P + p] = ci;
    float nr = fmaf(lTr, cr, fmaf(-lTi, ci, vr[u]));
    float ni = fmaf(lTr, ci, fmaf(lTi, cr, vi[u]));
    cr = nr; ci = ni;
  }
}

// ---------------------------------------------------------------------------
// GEMM2 fused: 128x128 tile (2 chunks), dbuf LDS, counted-vmcnt barriers.
// A = x_local(bf16, depth-2 reg pipeline) + pow*carry fixup (fp32, depth-1).
// B via load_lds, FRAGMENT-MAJOR (conflict-free). grid (L/128, H/128) = (256, 2).
// ---------------------------------------------------------------------------
__global__ __launch_bounds__(256) void k_gemm2f(const unsigned short* __restrict__ Xl,
                                                const unsigned short* __restrict__ Ccat,
                                                const float* __restrict__ powr,
                                                const float* __restrict__ powi,
                                                const float* __restrict__ car,
                                                const float* __restrict__ cai,
                                                const float* __restrict__ sig,
                                                const float* __restrict__ Dv,
                                                float* __restrict__ out) {
  constexpr int K = 512, NIT = K / 32;
  __shared__ __align__(16) char smem[36864];
  unsigned short* sA[2] = {(unsigned short*)smem, (unsigned short*)smem + 5120};
  unsigned short* sB[2] = {(unsigned short*)smem + 10240, (unsigned short*)smem + 14336};
  const int tid = threadIdx.x;
  const int lane = tid & 63;
  const int wave = tid >> 6;
  const int wr = (wave >> 1) * 64, wc = (wave & 1) * 64;
  const int m0 = blockIdx.x * 128, n0 = blockIdx.y * 128;
  const int ar = tid >> 1, aq = (tid & 1) * 16;   // row 0..127, 16-short half (8 pairs)
  const int t_ = ar & 63;
  const int cc = blockIdx.x * 2 + (ar >> 6);
  const int brow = ((tid >> 6) << 4) | (tid & 15);
  const int bko = ((tid >> 4) & 3) * 8;
  const int frow = lane & 15, fk = (lane >> 4) * 8;
  const int hb = (wave & 1) * 2048;
  f32x4 acc[4][4];
#pragma unroll
  for (int i = 0; i < 4; i++)
#pragma unroll
    for (int j = 0; j < 4; j++) acc[i][j] = (f32x4){0.f, 0.f, 0.f, 0.f};

  uint4 x0a, x1a, x0b, x1b;                       // depth-2 Xl stream
  float4 pr0, pr1, pi0, pi1, cr0, cr1, ci0, ci1;  // depth-1 pow/carry (L2-resident)
  const unsigned short* xbase = Xl + (size_t)(m0 + ar) * N1 + aq;
  const float* prb = powr + t_ * P;
  const float* pib = powi + t_ * P;
  const float* crb = car + cc * P;
  const float* cib = cai + cc * P;
#define LOAD_X(A0, A1, k0) { \
    A0 = *(const uint4*)(xbase + (k0)); A1 = *(const uint4*)(xbase + (k0) + 8); }
#define LOAD_PC(k0) { const int p0_ = ((k0) >> 1) + (tid & 1) * 8; \
    pr0 = *(const float4*)(prb + p0_); pr1 = *(const float4*)(prb + p0_ + 4); \
    pi0 = *(const float4*)(pib + p0_); pi1 = *(const float4*)(pib + p0_ + 4); \
    cr0 = *(const float4*)(crb + p0_); cr1 = *(const float4*)(crb + p0_ + 4); \
    ci0 = *(const float4*)(cib + p0_); ci1 = *(const float4*)(cib + p0_ + 4); }
#define WRITE_A2(XA, XB, dst) { \
    unsigned xw[8] = {XA.x, XA.y, XA.z, XA.w, XB.x, XB.y, XB.z, XB.w}; \
    float pr_[8] = {pr0.x, pr0.y, pr0.z, pr0.w, pr1.x, pr1.y, pr1.z, pr1.w}; \
    float pi_[8] = {pi0.x, pi0.y, pi0.z, pi0.w, pi1.x, pi1.y, pi1.z, pi1.w}; \
    float cr_[8] = {cr0.x, cr0.y, cr0.z, cr0.w, cr1.x, cr1.y, cr1.z, cr1.w}; \
    float ci_[8] = {ci0.x, ci0.y, ci0.z, ci0.w, ci1.x, ci1.y, ci1.z, ci1.w}; \
    unsigned wo[8]; \
    _Pragma("unroll") for (int j_ = 0; j_ < 8; j_++) { \
      float xgr = bf_lo(xw[j_]) + (pr_[j_] * cr_[j_] - pi_[j_] * ci_[j_]); \
      float xgi = bf_hi(xw[j_]) + (pr_[j_] * ci_[j_] + pi_[j_] * cr_[j_]); \
      wo[j_] = f2bf(xgr) | (f2bf(xgi) << 16); } \
    uint4 w0, w1; \
    w0.x = wo[0]; w0.y = wo[1]; w0.z = wo[2]; w0.w = wo[3]; \
    w1.x = wo[4]; w1.y = wo[5]; w1.z = wo[6]; w1.w = wo[7]; \
    *(uint4*)((dst) + ar * LDA + aq) = w0; *(uint4*)((dst) + ar * LDA + aq + 8) = w1; }
#define ISSUE_B2(k0, buf) { \
    gload_lds16(Ccat + (size_t)(n0 + brow) * K + (k0) + bko, sB[buf] + tid * 8); \
    gload_lds16(Ccat + (size_t)(n0 + 64 + brow) * K + (k0) + bko, sB[buf] + 2048 + tid * 8); }

  // prologue: issue order [X(k0),X(k32),PC(k0), B(k0), X(k64),PC(k32)] ->
  // wait B => vmcnt(10) (leaves X'(2)+PC'(8)).
  LOAD_X(x0a, x1a, 0);
  LOAD_X(x0b, x1b, 32);
  LOAD_PC(0);
  VMEM_FENCE();
  ISSUE_B2(0, 0);
  VMEM_FENCE();
  WRITE_A2(x0a, x1a, sA[0]);
  LOAD_X(x0a, x1a, 64);
  LOAD_PC(32);
  KBAR(10);
#pragma unroll
  for (int it = 0; it < NIT; it++) {
    const int cur = it & 1, nxt = cur ^ 1;
    if (it + 1 < NIT) {
      if (((it + 1) & 1) == 0) { WRITE_A2(x0a, x1a, sA[nxt]); } else { WRITE_A2(x0b, x1b, sA[nxt]); }
      ISSUE_B2((it + 1) * 32, nxt);
    }
    VMEM_FENCE();
    if (it + 3 < NIT) {
      if (((it + 3) & 1) == 0) { LOAD_X(x0a, x1a, (it + 3) * 32); } else { LOAD_X(x0b, x1b, (it + 3) * 32); }
    }
    if (it + 2 < NIT) LOAD_PC((it + 2) * 32);
    short8 af[4], bfr[4];
#pragma unroll
    for (int i = 0; i < 4; i++) af[i] = *(const short8*)(sA[cur] + (wr + i * 16 + frow) * LDA + fk);
#pragma unroll
    for (int j = 0; j < 4; j++) bfr[j] = *(const short8*)(sB[cur] + hb + (j * 64 + lane) * 8);
#pragma unroll
    for (int i = 0; i < 4; i++)
#pragma unroll
      for (int j = 0; j < 4; j++)
        acc[i][j] = __builtin_amdgcn_mfma_f32_16x16x32_bf16(af[i], bfr[j], acc[i][j], 0, 0, 0);
    if (it + 1 < NIT) {
      if (it + 3 < NIT) { KBAR(10); }
      else if (it + 2 < NIT) { KBAR(8); }
      else { KBAR(0); }
    }
  }

  const int crow = wr + (lane >> 4) * 4, ccol = wc + (lane & 15);
  float dcol[4];
#pragma unroll
  for (int j = 0; j < 4; j++) dcol[j] = Dv[n0 + ccol + j * 16];
#pragma unroll
  for (int i = 0; i < 4; i++)
#pragma unroll
    for (int j = 0; j < 4; j++) {
      int col = n0 + ccol + j * 16;
#pragma unroll
      for (int g = 0; g < 4; g++) {
        int row = m0 + crow + i * 16 + g;
        out[(size_t)row * H + col] = acc[i][j][g] + dcol[j] * sig[(size_t)row * H + col];
      }
    }
#undef LOAD_X
#undef LOAD_PC
#undef WRITE_A2
#undef ISSUE_B2
}

// ---------------------------------------------------------------------------
// Launch
// ---------------------------------------------------------------------------
extern "C" void kernel_launch(void* const* d_in, const int* in_sizes, int n_in,
                              void* d_out, int out_size, void* d_ws, size_t ws_size,
                              hipStream_t stream) {
  const float* sig = (const float*)d_in[0];   // (L,H)
  const float* lam = (const float*)d_in[1];   // (P,2)
  const float* Bri = (const float*)d_in[2];   // (P,H,2)
  const float* Cri = (const float*)d_in[3];   // (H,P,2)
  const float* Dv  = (const float*)d_in[4];   // (H,)
  const float* lst = (const float*)d_in[5];   // (P,)
  float* out = (float*)d_out;

  unsigned short* Bcat = (unsigned short*)d_ws;             // N1*H bf16
  unsigned short* Ccat = Bcat + (size_t)N1 * H;             // H*N1 bf16
  unsigned short* Xl   = Ccat + (size_t)H * N1;             // L*N1 bf16 (x_local)
  float* powr = (float*)(Xl + (size_t)L * N1);              // T*P
  float* powi = powr + T * P;
  float* Sr   = powi + T * P;                               // NC*P
  float* Si   = Sr + NC * P;
  float* car  = Si + NC * P;
  float* cai  = car + NC * P;

  k_prep<<<(2 * N1 * H + T * P) / 256, 256, 0, stream>>>(lam, lst, Bri, Cri,
                                                         Bcat, Ccat, powr, powi);
  dim3 g1(L / 128, N1 / 128);
  k_gemm1s<<<g1, 256, 0, stream>>>(sig, Bcat, lam, lst, Xl, Sr, Si);
  k_carry2<<<NC / 2, 64, 0, stream>>>(lam, lst, Sr, Si, car, cai);
  dim3 g2(L / 128, H / 128);
  k_gemm2f<<<g2, 256, 0, stream>>>(Xl, Ccat, powr, powi, car, cai, sig, Dv, out);
}